// Round 2
// baseline (89.507 us; speedup 1.0000x reference)
//
#include <hip/hip_runtime.h>

#define NMS_TH 0.7

__device__ __forceinline__ unsigned long long readlane64(unsigned long long x,
                                                         int l) {
    unsigned int lo = __builtin_amdgcn_readlane((unsigned int)x, l);
    unsigned int hi = __builtin_amdgcn_readlane((unsigned int)(x >> 32), l);
    return ((unsigned long long)hi << 32) | lo;
}

// ---------------------------------------------------------------------------
// Kernel A: fp64 corners + fp32 corners + fp64 areas + packed fp32 AABB.
// (byte-identical to round 1 — not under test)
// ---------------------------------------------------------------------------
__global__ void corners_kernel(const float* __restrict__ boxes,
                               double* __restrict__ cor,    // N*8 fp64
                               float* __restrict__ cor32,   // N*8 fp32
                               double* __restrict__ areas,  // N fp64
                               float4* __restrict__ aabb4,  // N
                               float* __restrict__ areaf,   // N fp32
                               int N) {
    int i = blockIdx.x * blockDim.x + threadIdx.x;
    if (i >= N) return;
    double xc = boxes[i * 5 + 0];
    double yc = boxes[i * 5 + 1];
    double w  = boxes[i * 5 + 2];
    double h  = boxes[i * 5 + 3];
    double t  = boxes[i * 5 + 4];
    double th = t * 0.017453292519943295;  // pi/180
    double c = cos(th), s = sin(th);
    const double lx[4] = {0.5, -0.5, -0.5, 0.5};
    const double ly[4] = {0.5, 0.5, -0.5, -0.5};
    double xmn = 1e30, xmx = -1e30, ymn = 1e30, ymx = -1e30;
#pragma unroll
    for (int k = 0; k < 4; ++k) {
        double x = xc + lx[k] * w * c - ly[k] * h * s;
        double y = yc + lx[k] * w * s + ly[k] * h * c;
        cor[i * 8 + k * 2 + 0] = x;
        cor[i * 8 + k * 2 + 1] = y;
        cor32[i * 8 + k * 2 + 0] = (float)x;
        cor32[i * 8 + k * 2 + 1] = (float)y;
        xmn = fmin(xmn, x); xmx = fmax(xmx, x);
        ymn = fmin(ymn, y); ymx = fmax(ymx, y);
    }
    areas[i] = w * h;
    aabb4[i] = make_float4((float)xmn, (float)xmx, (float)ymn, (float)ymx);
    areaf[i] = (float)(w * h);
}

// ---------------------------------------------------------------------------
// Convex-quad intersection area via Green's theorem — fp64 exact version.
// ---------------------------------------------------------------------------
__device__ __forceinline__ double clip_sum(const double* __restrict__ px,
                                           const double* __restrict__ py,
                                           const double* __restrict__ qx,
                                           const double* __restrict__ qy) {
    double acc = 0.0;
#pragma unroll
    for (int e = 0; e < 4; ++e) {
        double x0 = px[e], y0 = py[e];
        double x1 = px[(e + 1) & 3], y1 = py[(e + 1) & 3];
        double dx = x1 - x0, dy = y1 - y0;
        double t0 = 0.0, t1 = 1.0;
        bool empty = false;
#pragma unroll
        for (int f = 0; f < 4; ++f) {
            double ex0 = qx[f], ey0 = qy[f];
            double ex1 = qx[(f + 1) & 3], ey1 = qy[(f + 1) & 3];
            double edx = ex1 - ex0, edy = ey1 - ey0;
            double f0 = edx * (y0 - ey0) - edy * (x0 - ex0);
            double f1 = edx * (y1 - ey0) - edy * (x1 - ex0);
            double df = f1 - f0;
            if (df > 0.0) {
                t0 = fmax(t0, -f0 / df);
            } else if (df < 0.0) {
                t1 = fmin(t1, -f0 / df);
            } else if (f0 < 0.0) {
                empty = true;
            }
        }
        if (!empty && t0 < t1) {
            double ax = x0 + t0 * dx, ay = y0 + t0 * dy;
            double bx = x0 + t1 * dx, by = y0 + t1 * dy;
            acc += ax * by - bx * ay;
        }
    }
    return acc;
}

__device__ __forceinline__ bool exact_suppress64(const double* __restrict__ cor,
                                                 const double* __restrict__ areas,
                                                 int i, int j) {
    double px[4], py[4], qx[4], qy[4];
#pragma unroll
    for (int k = 0; k < 4; ++k) {
        px[k] = cor[i * 8 + k * 2 + 0];
        py[k] = cor[i * 8 + k * 2 + 1];
        qx[k] = cor[j * 8 + k * 2 + 0];
        qy[k] = cor[j * 8 + k * 2 + 1];
    }
    double inter = 0.5 * (clip_sum(px, py, qx, qy) + clip_sum(qx, qy, px, py));
    inter = fmax(inter, 0.0);
    double uni = areas[i] + areas[j] - inter;
    double iou = inter / fmax(uni, 1e-8);
    return iou > NMS_TH;
}

// ---------------------------------------------------------------------------
// fp32 fast-path clip (hardware rcp, ~1 ulp — inside the decision band).
// ---------------------------------------------------------------------------
__device__ __forceinline__ float clip_sum_f32(const float* __restrict__ px,
                                              const float* __restrict__ py,
                                              const float* __restrict__ qx,
                                              const float* __restrict__ qy) {
    float acc = 0.0f;
#pragma unroll
    for (int e = 0; e < 4; ++e) {
        float x0 = px[e], y0 = py[e];
        float x1 = px[(e + 1) & 3], y1 = py[(e + 1) & 3];
        float dx = x1 - x0, dy = y1 - y0;
        float t0 = 0.0f, t1 = 1.0f;
        bool empty = false;
#pragma unroll
        for (int f = 0; f < 4; ++f) {
            float ex0 = qx[f], ey0 = qy[f];
            float ex1 = qx[(f + 1) & 3], ey1 = qy[(f + 1) & 3];
            float edx = ex1 - ex0, edy = ey1 - ey0;
            float f0 = edx * (y0 - ey0) - edy * (x0 - ex0);
            float f1 = edx * (y1 - ey0) - edy * (x1 - ex0);
            float df = f1 - f0;
            if (df > 0.0f) {
                t0 = fmaxf(t0, -f0 * __builtin_amdgcn_rcpf(df));
            } else if (df < 0.0f) {
                t1 = fminf(t1, -f0 * __builtin_amdgcn_rcpf(df));
            } else if (f0 < 0.0f) {
                empty = true;
            }
        }
        if (!empty && t0 < t1) {
            float ax = x0 + t0 * dx, ay = y0 + t0 * dy;
            float bx = x0 + t1 * dx, by = y0 + t1 * dy;
            acc += ax * by - bx * ay;
        }
    }
    return acc;
}

// ---------------------------------------------------------------------------
// Kernel B: WAVE-PER-ROW (byte-identical to round 1 — not under test).
// ---------------------------------------------------------------------------
__global__ __launch_bounds__(256) void iou_wave_kernel(
    const float4* __restrict__ aabb4, const float* __restrict__ areaf,
    const float4* __restrict__ cor32v, const double* __restrict__ cor,
    const double* __restrict__ areas, unsigned long long* __restrict__ mask,
    unsigned long long* __restrict__ rowinfo, int N) {
    __shared__ unsigned short cand[4][2048];       // worst case N-1 cands/row
    __shared__ unsigned long long lmask[4][32];

    int w = threadIdx.x >> 6;
    int lane = threadIdx.x & 63;
    int i = blockIdx.x * 4 + w;
    if (i >= N) return;  // wave-uniform exit

    if (lane < 32) lmask[w][lane] = 0ULL;

    float4 bi = aabb4[i];
    float iaf = areaf[i];
    float thr_i = 0.699f * iaf;

    // own fp32 corners via two float4 loads
    float4 c01 = cor32v[i * 2 + 0];
    float4 c23 = cor32v[i * 2 + 1];
    float px[4] = {c01.x, c01.z, c23.x, c23.z};
    float py[4] = {c01.y, c01.w, c23.y, c23.w};

    // -------- Phase 1: AABB filter, ballot-compacted candidate list -------
    int cnt = 0;  // wave-uniform (derived from ballots only)
    for (int jbase = (i + 1) & ~63; jbase < N; jbase += 64) {
        int j = jbase + lane;
        bool pass = false;
        if (j > i && j < N) {
            float4 bj = aabb4[j];
            float iw = fminf(bi.y, bj.y) - fmaxf(bi.x, bj.x);
            float ih = fminf(bi.w, bj.w) - fmaxf(bi.z, bj.z);
            if (iw > 0.0f && ih > 0.0f) {
                float jaf = areaf[j];
                float ub = fminf(iw * ih, fminf(iaf, jaf));
                pass = (1.699f * ub >= thr_i + 0.699f * jaf);
            }
        }
        unsigned long long b = __ballot(pass);
        if (b) {
            unsigned long long lt = (1ULL << lane) - 1ULL;  // lanes below me
            int pos = cnt + __popcll(b & lt);
            if (pass) cand[w][pos] = (unsigned short)j;
            cnt += __popcll(b);
        }
    }

    __builtin_amdgcn_wave_barrier();  // keep compiler from reordering LDS ops

    // -------- Phase 2: fp32 clip, rare fp64 fallback ----------------------
    for (int k = lane; k < cnt; k += 64) {
        int j = (int)cand[w][k];
        float4 q01 = cor32v[j * 2 + 0];
        float4 q23 = cor32v[j * 2 + 1];
        float qx[4] = {q01.x, q01.z, q23.x, q23.z};
        float qy[4] = {q01.y, q01.w, q23.y, q23.w};
        float inter =
            0.5f * (clip_sum_f32(px, py, qx, qy) + clip_sum_f32(qx, qy, px, py));
        inter = fmaxf(inter, 0.0f);
        float uni = iaf + areaf[j] - inter;
        float iou = inter / fmaxf(uni, 1e-8f);
        bool sup;
        if (fabsf(iou - 0.7f) > 5e-3f)
            sup = iou > 0.7f;                          // fp32 decision
        else
            sup = exact_suppress64(cor, areas, i, j);  // rare fallback
        if (sup) atomicOr(&lmask[w][j >> 6], 1ULL << (j & 63));
    }

    __builtin_amdgcn_wave_barrier();

    // -------- Epilogue: mask row + rowinfo (count + first 6 targets) ------
    unsigned long long wv = (lane < 32) ? lmask[w][lane] : 0ULL;
    unsigned long long nzb = __ballot((lane < 32) && (wv != 0ULL));
    if (lane < 32) mask[(size_t)i * 32 + lane] = wv;

    if (lane == 0) {
        int total = 0, nf = 0;
        unsigned short tg[6] = {0, 0, 0, 0, 0, 0};
        unsigned long long nz = nzb;
        while (nz) {
            int wgi = __ffsll(nz) - 1;
            nz &= nz - 1ULL;
            unsigned long long v = lmask[w][wgi];
            total += __popcll(v);
            while (v && nf < 6) {
                int b = __ffsll(v) - 1;
                v &= v - 1ULL;
                tg[nf++] = (unsigned short)(wgi * 64 + b);
            }
        }
        unsigned long long i0 =
            (unsigned long long)(unsigned short)total |
            ((unsigned long long)tg[0] << 16) |
            ((unsigned long long)tg[1] << 32) |
            ((unsigned long long)tg[2] << 48);
        unsigned long long i1 = (unsigned long long)tg[3] |
                                ((unsigned long long)tg[4] << 16) |
                                ((unsigned long long)tg[5] << 32);
        rowinfo[2 * i] = i0;
        rowinfo[2 * i + 1] = i1;
    }
}

// ---------------------------------------------------------------------------
// Kernel C: edge-list greedy sweep — REWRITTEN BRANCHLESS.
// Theory: this single-wave serial loop is the hidden ~39 µs (just under the
// top-5 cutoff both rounds).  The loop-carried chain is only {bb -> ffs ->
// readlane(ri0) -> dm}; everything uniform stays in SGPRs (ballot/readlane
// results), target decode is unconditional with sentinel 2048 (-> lane 32,
// whose 'removed' word is never read), and per-lane 'removed' updates are
// VALU ops OFF the serial chain.  Only the rare cnt>=4 path keeps a uniform
// branch.  Expected 3-6x on this kernel.
// ---------------------------------------------------------------------------
__global__ __launch_bounds__(64, 1) void greedy_kernel(
    const unsigned long long* __restrict__ mask,
    const unsigned long long* __restrict__ rowinfo, int* __restrict__ out,
    int N, int topn) {
    constexpr int WORDS = 32;
    int lane = threadIdx.x;
    unsigned long long removed = 0ULL;
    unsigned long long lanebit_cache = 1ULL;  // unused placeholder removed below

    unsigned long long ri0[WORDS], ri1[WORDS];
    const ulonglong2* rv = (const ulonglong2*)rowinfo;
#pragma unroll
    for (int c = 0; c < WORDS; ++c) {
        int r = c * 64 + lane;
        if (r < N) {
            ulonglong2 v = rv[r];
            ri0[c] = v.x;
            ri1[c] = v.y;
        } else {
            ri0[c] = 0ULL;
            ri1[c] = 0ULL;
        }
    }
    (void)lanebit_cache;

#pragma unroll
    for (int c = 0; c < WORDS; ++c) {
        unsigned long long bits = __ballot((ri0[c] & 0xffffULL) != 0ULL);
        if (!bits) continue;
        unsigned long long dm = readlane64(removed, c);  // uniform copy
        unsigned long long todo = bits;
        for (;;) {
            unsigned long long bb = todo & ~dm;
            if (!bb) break;
            int b = __ffsll(bb) - 1;                 // uniform (SALU s_ff1)
            todo &= ~(1ULL << b);
            unsigned long long i0 = readlane64(ri0[c], b);
            int cnt = (int)(i0 & 0xffffULL);

            // --- branchless decode of up to 3 inline targets --------------
            // sentinel 2048: word 32 -> lane 32 ('removed' there is dead),
            // and (2048>>6)==32 != c so dm is untouched.
            int t0 = (int)((i0 >> 16) & 0xffffULL);
            int t1 = (cnt >= 2) ? (int)((i0 >> 32) & 0xffffULL) : 2048;
            int t2 = (cnt >= 3) ? (int)((i0 >> 48) & 0xffffULL) : 2048;

            // dm updates (serial chain carrier) — pure SALU cselect/or tree
            unsigned long long a0 =
                ((t0 >> 6) == c) ? (1ULL << (t0 & 63)) : 0ULL;
            unsigned long long a1 =
                ((t1 >> 6) == c) ? (1ULL << (t1 & 63)) : 0ULL;
            unsigned long long a2 =
                ((t2 >> 6) == c) ? (1ULL << (t2 & 63)) : 0ULL;

            // per-lane removed updates — VALU, off the serial chain
            unsigned long long r0 =
                (lane == (t0 >> 6)) ? (1ULL << (t0 & 63)) : 0ULL;
            unsigned long long r1 =
                (lane == (t1 >> 6)) ? (1ULL << (t1 & 63)) : 0ULL;
            unsigned long long r2 =
                (lane == (t2 >> 6)) ? (1ULL << (t2 & 63)) : 0ULL;
            removed |= (r0 | r1) | r2;

            if (cnt >= 4) {  // uniform branch, uncommon
                if (cnt <= 6) {
                    unsigned long long i1 = readlane64(ri1[c], b);
                    int t3 = (int)(i1 & 0xffffULL);
                    int t4 = (cnt >= 5) ? (int)((i1 >> 16) & 0xffffULL) : 2048;
                    int t5 = (cnt >= 6) ? (int)((i1 >> 32) & 0xffffULL) : 2048;
                    unsigned long long a3 =
                        ((t3 >> 6) == c) ? (1ULL << (t3 & 63)) : 0ULL;
                    unsigned long long a4 =
                        ((t4 >> 6) == c) ? (1ULL << (t4 & 63)) : 0ULL;
                    unsigned long long a5 =
                        ((t5 >> 6) == c) ? (1ULL << (t5 & 63)) : 0ULL;
                    a0 |= (a3 | a4) | a5;
                    unsigned long long r3 =
                        (lane == (t3 >> 6)) ? (1ULL << (t3 & 63)) : 0ULL;
                    unsigned long long r4 =
                        (lane == (t4 >> 6)) ? (1ULL << (t4 & 63)) : 0ULL;
                    unsigned long long r5 =
                        (lane == (t5 >> 6)) ? (1ULL << (t5 & 63)) : 0ULL;
                    removed |= (r3 | r4) | r5;
                    dm |= (a0 | a1) | a2;
                } else {
                    // rare: >6 targets -> OR in the full mask row, then
                    // refresh dm from the authoritative distributed state.
                    int r = c * 64 + b;
                    removed |= mask[(size_t)r * WORDS + (lane & 31)];
                    dm = readlane64(removed, c);
                }
            } else {
                dm |= (a0 | a1) | a2;
            }
        }
    }

    unsigned long long keepw = 0ULL;
    if (lane < WORDS) {
        keepw = ~removed;
        int base = lane * 64;
        int valid = N - base;
        if (valid <= 0)
            keepw = 0ULL;
        else if (valid < 64)
            keepw &= ((1ULL << valid) - 1ULL);
    }

    int pc = __popcll(keepw);
    int scan = pc;
#pragma unroll
    for (int off = 1; off < 64; off <<= 1) {
        int v = __shfl_up(scan, off);
        if (lane >= off) scan += v;
    }
    int base_out = scan - pc;
    int total = __shfl(scan, WORDS - 1);

    if (lane < WORDS) {
        int pos = base_out;
        unsigned long long w = keepw;
        while (w) {
            int b = __ffsll(w) - 1;
            w &= w - 1ULL;
            if (pos < topn) out[pos] = lane * 64 + b;
            ++pos;
        }
    }
    for (int k = (total < topn ? total : topn) + lane; k < topn; k += 64)
        out[k] = -1;
}

// ---------------------------------------------------------------------------
extern "C" void kernel_launch(void* const* d_in, const int* in_sizes, int n_in,
                              void* d_out, int out_size, void* d_ws,
                              size_t ws_size, hipStream_t stream) {
    const float* boxes = (const float*)d_in[0];
    int N = in_sizes[0] / 5;  // 2000 (greedy requires N <= 2048)
    int topn = out_size;      // 1000

    char* ws = (char*)d_ws;
    size_t off = 0;
    double* cor = (double*)(ws + off);     off += (size_t)N * 8 * 8;    // 128000
    float* cor32 = (float*)(ws + off);     off += (size_t)N * 8 * 4;    // 64000
    double* areas = (double*)(ws + off);   off += (size_t)N * 8;        // 16000
    unsigned long long* mask =
        (unsigned long long*)(ws + off);   off += (size_t)N * 32 * 8;   // 512000
    float4* aabb4 = (float4*)(ws + off);   off += (size_t)N * 16;       // 32000
    float* areaf = (float*)(ws + off);     off += (size_t)N * 4;        // 8000
    unsigned long long* rowinfo =
        (unsigned long long*)(ws + off);   off += (size_t)N * 16;       // 32000

    corners_kernel<<<(N + 255) / 256, 256, 0, stream>>>(
        boxes, cor, cor32, areas, aabb4, areaf, N);
    iou_wave_kernel<<<(N + 3) / 4, 256, 0, stream>>>(
        aabb4, areaf, (const float4*)cor32, cor, areas, mask, rowinfo, N);
    greedy_kernel<<<1, 64, 0, stream>>>(mask, rowinfo, (int*)d_out, N, topn);
}

// Round 3
// 83.292 us; speedup vs baseline: 1.0746x; 1.0746x over previous
//
#include <hip/hip_runtime.h>
#include <math.h>

#define NMS_TH 0.7

__device__ __forceinline__ unsigned long long readlane64(unsigned long long x,
                                                         int l) {
    unsigned int lo = __builtin_amdgcn_readlane((unsigned int)x, l);
    unsigned int hi = __builtin_amdgcn_readlane((unsigned int)(x >> 32), l);
    return ((unsigned long long)hi << 32) | lo;
}

// ---------------------------------------------------------------------------
// f32 corners, bit-compatible with the reference's float32 corner math:
//   x = xc + lx*w*c - ly*h*s ; y = yc + lx*w*s + ly*h*c,
//   (lx,ly) = (.5,.5), (-.5,.5), (-.5,-.5), (.5,-.5)   [CCW]
// ---------------------------------------------------------------------------
__device__ __forceinline__ void make_corners(const float* __restrict__ b5,
                                             float* px, float* py) {
    float xc = b5[0], yc = b5[1], bw = b5[2], bh = b5[3], bt = b5[4];
    float sn, cs;
    sincosf(bt * 0.017453292519943295f, &sn, &cs);
    float wx = 0.5f * bw * cs, wy = 0.5f * bw * sn;
    float hx = 0.5f * bh * sn, hy = 0.5f * bh * cs;
    px[0] = xc + wx - hx; py[0] = yc + wy + hy;
    px[1] = xc - wx - hx; py[1] = yc - wy + hy;
    px[2] = xc - wx + hx; py[2] = yc - wy - hy;
    px[3] = xc + wx + hx; py[3] = yc + wy - hy;
}

// ---------------------------------------------------------------------------
// Convex-quad intersection area via Green's theorem — fp64 exact version,
// operating on the (promoted) f32 corners.  Used only in the |iou-0.7|<=5e-3
// band; fp64 arithmetic on the same geometry the f32 path (and the reference)
// uses.
// ---------------------------------------------------------------------------
__device__ __forceinline__ double clip_sum64(const double* __restrict__ px,
                                             const double* __restrict__ py,
                                             const double* __restrict__ qx,
                                             const double* __restrict__ qy) {
    double acc = 0.0;
#pragma unroll
    for (int e = 0; e < 4; ++e) {
        double x0 = px[e], y0 = py[e];
        double x1 = px[(e + 1) & 3], y1 = py[(e + 1) & 3];
        double dx = x1 - x0, dy = y1 - y0;
        double t0 = 0.0, t1 = 1.0;
        bool empty = false;
#pragma unroll
        for (int f = 0; f < 4; ++f) {
            double ex0 = qx[f], ey0 = qy[f];
            double ex1 = qx[(f + 1) & 3], ey1 = qy[(f + 1) & 3];
            double edx = ex1 - ex0, edy = ey1 - ey0;
            double f0 = edx * (y0 - ey0) - edy * (x0 - ex0);
            double f1 = edx * (y1 - ey0) - edy * (x1 - ex0);
            double df = f1 - f0;
            if (df > 0.0) {
                t0 = fmax(t0, -f0 / df);
            } else if (df < 0.0) {
                t1 = fmin(t1, -f0 / df);
            } else if (f0 < 0.0) {
                empty = true;
            }
        }
        if (!empty && t0 < t1) {
            double ax = x0 + t0 * dx, ay = y0 + t0 * dy;
            double bx = x0 + t1 * dx, by = y0 + t1 * dy;
            acc += ax * by - bx * ay;
        }
    }
    return acc;
}

__device__ __forceinline__ bool exact_suppress_pts(const float* pxf,
                                                   const float* pyf,
                                                   const float* qxf,
                                                   const float* qyf,
                                                   double ai, double aj) {
    double px[4], py[4], qx[4], qy[4];
#pragma unroll
    for (int k = 0; k < 4; ++k) {
        px[k] = (double)pxf[k]; py[k] = (double)pyf[k];
        qx[k] = (double)qxf[k]; qy[k] = (double)qyf[k];
    }
    double inter = 0.5 * (clip_sum64(px, py, qx, qy) + clip_sum64(qx, qy, px, py));
    inter = fmax(inter, 0.0);
    double uni = ai + aj - inter;
    double iou = inter / fmax(uni, 1e-8);
    return iou > NMS_TH;
}

// ---------------------------------------------------------------------------
// fp32 fast-path clip (hardware rcp, ~1 ulp — inside the decision band).
// ---------------------------------------------------------------------------
__device__ __forceinline__ float clip_sum_f32(const float* __restrict__ px,
                                              const float* __restrict__ py,
                                              const float* __restrict__ qx,
                                              const float* __restrict__ qy) {
    float acc = 0.0f;
#pragma unroll
    for (int e = 0; e < 4; ++e) {
        float x0 = px[e], y0 = py[e];
        float x1 = px[(e + 1) & 3], y1 = py[(e + 1) & 3];
        float dx = x1 - x0, dy = y1 - y0;
        float t0 = 0.0f, t1 = 1.0f;
        bool empty = false;
#pragma unroll
        for (int f = 0; f < 4; ++f) {
            float ex0 = qx[f], ey0 = qy[f];
            float ex1 = qx[(f + 1) & 3], ey1 = qy[(f + 1) & 3];
            float edx = ex1 - ex0, edy = ey1 - ey0;
            float f0 = edx * (y0 - ey0) - edy * (x0 - ex0);
            float f1 = edx * (y1 - ey0) - edy * (x1 - ex0);
            float df = f1 - f0;
            if (df > 0.0f) {
                t0 = fmaxf(t0, -f0 * __builtin_amdgcn_rcpf(df));
            } else if (df < 0.0f) {
                t1 = fminf(t1, -f0 * __builtin_amdgcn_rcpf(df));
            } else if (f0 < 0.0f) {
                empty = true;
            }
        }
        if (!empty && t0 < t1) {
            float ax = x0 + t0 * dx, ay = y0 + t0 * dy;
            float bx = x0 + t1 * dx, by = y0 + t1 * dy;
            acc += ax * by - bx * ay;
        }
    }
    return acc;
}

// ---------------------------------------------------------------------------
// FUSED iou kernel — zero upstream dependencies, contention-immune.
// Block = 4 waves = rows 4b..4b+3.
//   Stage:   all 256 threads compute AABB+area for ALL N boxes from `boxes`
//            directly into LDS (no corners kernel, no global round-trip).
//   Phase 1: AABB scan entirely from LDS (immune to harness-fill L2 thrash),
//            ballot-compacted candidate list.
//   Phase 2: candidate corners RECOMPUTED in registers (~30 VALU ops,
//            contention-proof) instead of loading precomputed cor32.
//            fp32 clip decides unless |iou-0.7| <= 5e-3 -> fp64 on the same
//            f32 corners (no fp64 trig; rare).
// LDS: 32K aabb + 8K area + 16K cand + 1K lmask = 57.25 KB -> 2 blocks/CU.
// ---------------------------------------------------------------------------
__global__ __launch_bounds__(256) void iou_all_kernel(
    const float* __restrict__ boxes, unsigned long long* __restrict__ mask,
    unsigned long long* __restrict__ rowinfo, int N) {
    __shared__ float4 s_aabb[2048];
    __shared__ float s_area[2048];
    __shared__ unsigned short cand[4][2048];
    __shared__ unsigned long long lmask[4][32];

    int tid = threadIdx.x;
    int w = tid >> 6;
    int lane = tid & 63;
    int i = blockIdx.x * 4 + w;

    // -------- stage AABB + area for all boxes into LDS --------------------
    for (int j = tid; j < 2048; j += 256) {
        if (j < N) {
            const float* b = boxes + j * 5;
            float xc = b[0], yc = b[1], bw = b[2], bh = b[3], bt = b[4];
            float sn, cs;
            sincosf(bt * 0.017453292519943295f, &sn, &cs);
            float ex = 0.5f * (fabsf(bw * cs) + fabsf(bh * sn));
            float ey = 0.5f * (fabsf(bw * sn) + fabsf(bh * cs));
            s_aabb[j] = make_float4(xc - ex, xc + ex, yc - ey, yc + ey);
            s_area[j] = bw * bh;
        } else {
            s_aabb[j] = make_float4(1e30f, -1e30f, 1e30f, -1e30f);
            s_area[j] = 0.0f;
        }
    }
    if (lane < 32) lmask[w][lane] = 0ULL;
    __syncthreads();

    if (i >= N) return;  // wave-uniform; no __syncthreads below this point

    float4 bi = s_aabb[i];
    float iaf = s_area[i];
    float thr_i = 0.699f * iaf;

    // -------- Phase 1: LDS AABB scan, ballot-compacted candidates ---------
    int cnt = 0;  // wave-uniform (derived from ballots only)
    for (int jbase = (i + 1) & ~63; jbase < N; jbase += 64) {
        int j = jbase + lane;  // < 2048 always; j>=N slots hold empty AABBs
        bool pass = false;
        if (j > i) {
            float4 bj = s_aabb[j];
            float iw = fminf(bi.y, bj.y) - fmaxf(bi.x, bj.x);
            float ih = fminf(bi.w, bj.w) - fmaxf(bi.z, bj.z);
            if (iw > 0.0f && ih > 0.0f) {
                float jaf = s_area[j];
                float ub = fminf(iw * ih, fminf(iaf, jaf));
                pass = (1.699f * ub >= thr_i + 0.699f * jaf);
            }
        }
        unsigned long long b = __ballot(pass);
        if (b) {
            unsigned long long lt = (1ULL << lane) - 1ULL;
            int pos = cnt + __popcll(b & lt);
            if (pass) cand[w][pos] = (unsigned short)j;
            cnt += __popcll(b);
        }
    }

    __builtin_amdgcn_wave_barrier();  // order LDS ops within the wave

    // -------- Phase 2: recomputed corners, fp32 clip, rare fp64 -----------
    if (cnt) {
        const float* bi5 = boxes + i * 5;  // broadcast load (L2)
        float px[4], py[4];
        make_corners(bi5, px, py);
        double ai64 = (double)bi5[2] * (double)bi5[3];

        for (int k = lane; k < cnt; k += 64) {
            int j = (int)cand[w][k];
            const float* bj5 = boxes + j * 5;
            float qx[4], qy[4];
            make_corners(bj5, qx, qy);
            float jaf = s_area[j];
            float inter = 0.5f * (clip_sum_f32(px, py, qx, qy) +
                                  clip_sum_f32(qx, qy, px, py));
            inter = fmaxf(inter, 0.0f);
            float uni = iaf + jaf - inter;
            float iou = inter / fmaxf(uni, 1e-8f);
            bool sup;
            if (fabsf(iou - 0.7f) > 5e-3f) {
                sup = iou > 0.7f;  // fp32 decision
            } else {
                double aj64 = (double)bj5[2] * (double)bj5[3];
                sup = exact_suppress_pts(px, py, qx, qy, ai64, aj64);
            }
            if (sup) atomicOr(&lmask[w][j >> 6], 1ULL << (j & 63));
        }
    }

    __builtin_amdgcn_wave_barrier();

    // -------- Epilogue: mask row + rowinfo (count + first 6 targets) ------
    unsigned long long wv = (lane < 32) ? lmask[w][lane] : 0ULL;
    unsigned long long nzb = __ballot((lane < 32) && (wv != 0ULL));
    if (lane < 32) mask[(size_t)i * 32 + lane] = wv;

    if (lane == 0) {
        int total = 0, nf = 0;
        unsigned short tg[6] = {0, 0, 0, 0, 0, 0};
        unsigned long long nz = nzb;
        while (nz) {
            int wgi = __ffsll(nz) - 1;
            nz &= nz - 1ULL;
            unsigned long long v = lmask[w][wgi];
            total += __popcll(v);
            while (v && nf < 6) {
                int b = __ffsll(v) - 1;
                v &= v - 1ULL;
                tg[nf++] = (unsigned short)(wgi * 64 + b);
            }
        }
        unsigned long long i0 =
            (unsigned long long)(unsigned short)total |
            ((unsigned long long)tg[0] << 16) |
            ((unsigned long long)tg[1] << 32) |
            ((unsigned long long)tg[2] << 48);
        unsigned long long i1 = (unsigned long long)tg[3] |
                                ((unsigned long long)tg[4] << 16) |
                                ((unsigned long long)tg[5] << 32);
        rowinfo[2 * i] = i0;
        rowinfo[2 * i + 1] = i1;
    }
}

// ---------------------------------------------------------------------------
// Kernel C: edge-list greedy sweep — byte-identical logic to round 2
// (branchless SALU chain; not under test this round).
// ---------------------------------------------------------------------------
__global__ __launch_bounds__(64, 1) void greedy_kernel(
    const unsigned long long* __restrict__ mask,
    const unsigned long long* __restrict__ rowinfo, int* __restrict__ out,
    int N, int topn) {
    constexpr int WORDS = 32;
    int lane = threadIdx.x;
    unsigned long long removed = 0ULL;

    unsigned long long ri0[WORDS], ri1[WORDS];
    const ulonglong2* rv = (const ulonglong2*)rowinfo;
#pragma unroll
    for (int c = 0; c < WORDS; ++c) {
        int r = c * 64 + lane;
        if (r < N) {
            ulonglong2 v = rv[r];
            ri0[c] = v.x;
            ri1[c] = v.y;
        } else {
            ri0[c] = 0ULL;
            ri1[c] = 0ULL;
        }
    }

#pragma unroll
    for (int c = 0; c < WORDS; ++c) {
        unsigned long long bits = __ballot((ri0[c] & 0xffffULL) != 0ULL);
        if (!bits) continue;
        unsigned long long dm = readlane64(removed, c);  // uniform copy
        unsigned long long todo = bits;
        for (;;) {
            unsigned long long bb = todo & ~dm;
            if (!bb) break;
            int b = __ffsll(bb) - 1;  // uniform
            todo &= ~(1ULL << b);
            unsigned long long i0 = readlane64(ri0[c], b);
            int cnt = (int)(i0 & 0xffffULL);

            // branchless decode; sentinel 2048 -> word 32 (dead)
            int t0 = (int)((i0 >> 16) & 0xffffULL);
            int t1 = (cnt >= 2) ? (int)((i0 >> 32) & 0xffffULL) : 2048;
            int t2 = (cnt >= 3) ? (int)((i0 >> 48) & 0xffffULL) : 2048;

            unsigned long long a0 =
                ((t0 >> 6) == c) ? (1ULL << (t0 & 63)) : 0ULL;
            unsigned long long a1 =
                ((t1 >> 6) == c) ? (1ULL << (t1 & 63)) : 0ULL;
            unsigned long long a2 =
                ((t2 >> 6) == c) ? (1ULL << (t2 & 63)) : 0ULL;

            unsigned long long r0 =
                (lane == (t0 >> 6)) ? (1ULL << (t0 & 63)) : 0ULL;
            unsigned long long r1 =
                (lane == (t1 >> 6)) ? (1ULL << (t1 & 63)) : 0ULL;
            unsigned long long r2 =
                (lane == (t2 >> 6)) ? (1ULL << (t2 & 63)) : 0ULL;
            removed |= (r0 | r1) | r2;

            if (cnt >= 4) {  // uniform branch, uncommon
                if (cnt <= 6) {
                    unsigned long long i1 = readlane64(ri1[c], b);
                    int t3 = (int)(i1 & 0xffffULL);
                    int t4 = (cnt >= 5) ? (int)((i1 >> 16) & 0xffffULL) : 2048;
                    int t5 = (cnt >= 6) ? (int)((i1 >> 32) & 0xffffULL) : 2048;
                    unsigned long long a3 =
                        ((t3 >> 6) == c) ? (1ULL << (t3 & 63)) : 0ULL;
                    unsigned long long a4 =
                        ((t4 >> 6) == c) ? (1ULL << (t4 & 63)) : 0ULL;
                    unsigned long long a5 =
                        ((t5 >> 6) == c) ? (1ULL << (t5 & 63)) : 0ULL;
                    a0 |= (a3 | a4) | a5;
                    unsigned long long r3 =
                        (lane == (t3 >> 6)) ? (1ULL << (t3 & 63)) : 0ULL;
                    unsigned long long r4 =
                        (lane == (t4 >> 6)) ? (1ULL << (t4 & 63)) : 0ULL;
                    unsigned long long r5 =
                        (lane == (t5 >> 6)) ? (1ULL << (t5 & 63)) : 0ULL;
                    removed |= (r3 | r4) | r5;
                    dm |= (a0 | a1) | a2;
                } else {
                    int r = c * 64 + b;
                    removed |= mask[(size_t)r * WORDS + (lane & 31)];
                    dm = readlane64(removed, c);
                }
            } else {
                dm |= (a0 | a1) | a2;
            }
        }
    }

    unsigned long long keepw = 0ULL;
    if (lane < WORDS) {
        keepw = ~removed;
        int base = lane * 64;
        int valid = N - base;
        if (valid <= 0)
            keepw = 0ULL;
        else if (valid < 64)
            keepw &= ((1ULL << valid) - 1ULL);
    }

    int pc = __popcll(keepw);
    int scan = pc;
#pragma unroll
    for (int off = 1; off < 64; off <<= 1) {
        int v = __shfl_up(scan, off);
        if (lane >= off) scan += v;
    }
    int base_out = scan - pc;
    int total = __shfl(scan, WORDS - 1);

    if (lane < WORDS) {
        int pos = base_out;
        unsigned long long w = keepw;
        while (w) {
            int b = __ffsll(w) - 1;
            w &= w - 1ULL;
            if (pos < topn) out[pos] = lane * 64 + b;
            ++pos;
        }
    }
    for (int k = (total < topn ? total : topn) + lane; k < topn; k += 64)
        out[k] = -1;
}

// ---------------------------------------------------------------------------
extern "C" void kernel_launch(void* const* d_in, const int* in_sizes, int n_in,
                              void* d_out, int out_size, void* d_ws,
                              size_t ws_size, hipStream_t stream) {
    const float* boxes = (const float*)d_in[0];
    int N = in_sizes[0] / 5;  // 2000 (greedy requires N <= 2048)
    int topn = out_size;      // 1000

    char* ws = (char*)d_ws;
    size_t off = 0;
    unsigned long long* mask =
        (unsigned long long*)(ws + off);   off += (size_t)N * 32 * 8;   // 512000
    unsigned long long* rowinfo =
        (unsigned long long*)(ws + off);   off += (size_t)N * 16;       // 32000

    iou_all_kernel<<<(N + 3) / 4, 256, 0, stream>>>(boxes, mask, rowinfo, N);
    greedy_kernel<<<1, 64, 0, stream>>>(mask, rowinfo, (int*)d_out, N, topn);
}